// Round 1
// baseline (9373.528 us; speedup 1.0000x reference)
//
#include <hip/hip_runtime.h>
#include <hip/hip_bf16.h>

typedef __attribute__((ext_vector_type(8))) short short8;
typedef __attribute__((ext_vector_type(4))) float f32x4;

#define MFMA16(a, b, c) __builtin_amdgcn_mfma_f32_16x16x32_bf16((a), (b), (c), 0, 0, 0)

// sizes
#define B_ 64
#define T_ 512
#define STATE_ 512
#define NG 16   // workgroups per row-group
#define NGROUPS 4

// ws layout (bytes)
#define CNT_OFF   0u          // 4 groups * 1536 phases * 4B = 24576
#define HBUF_OFF  24576u      // 2 * 64 * 512 * 2B = 131072
#define CAT_OFF   155648u     // 512*64*1024*2 = 67108864
#define W0F_OFF   67264512u   // 1048576
#define W1F_OFF   68313088u   // 524288
#define WAF_OFF   68837376u   // 1048576
#define WBT_OFF   69885952u   // 2097152
// end: 71983104

__device__ __forceinline__ short f2bf(float f) {
  unsigned u = __float_as_uint(f);
  unsigned r = (u + 0x7fffu + ((u >> 16) & 1u)) >> 16;
  return (short)r;
}

// ---------------------------------------------------------------------------
// Weight packing: fp32 -> bf16, MFMA B-fragment order for W0 / W1 / Wout[:, :512],
// plus transposed row-major copy of Wout[:, 512:] for the logits GEMM.
// Fragment blob layout for (K,N) matrix: idx = ((cb*(K/32) + s)*64 + l)*8 + j
//   holds W[s*32 + (l>>4)*8 + j][cb*16 + (l&15)]
// ---------------------------------------------------------------------------
__global__ void pack_weights(const float* __restrict__ W0, const float* __restrict__ W1,
                             const float* __restrict__ Wout,
                             short* __restrict__ W0f, short* __restrict__ W1f,
                             short* __restrict__ Waf, short* __restrict__ WbT) {
  const int total = 524288 + 262144 + 524288 + 1048576;
  for (int i = blockIdx.x * blockDim.x + threadIdx.x; i < total; i += gridDim.x * blockDim.x) {
    if (i < 524288) {                       // W0f: K=1024 (S=32), N=512
      int j = i & 7, l = (i >> 3) & 63, rest = i >> 9;
      int s = rest & 31, cb = rest >> 5;
      int k = s * 32 + ((l >> 4) << 3) + j, n = (cb << 4) + (l & 15);
      W0f[i] = f2bf(W0[k * 512 + n]);
    } else if (i < 786432) {                // W1f: K=512 (S=16), N=512
      int ii = i - 524288;
      int j = ii & 7, l = (ii >> 3) & 63, rest = ii >> 9;
      int s = rest & 15, cb = rest >> 4;
      int k = s * 32 + ((l >> 4) << 3) + j, n = (cb << 4) + (l & 15);
      W1f[ii] = f2bf(W1[k * 512 + n]);
    } else if (i < 1310720) {               // Waf: Wout[:, :512], K=1024 (S=32)
      int ii = i - 786432;
      int j = ii & 7, l = (ii >> 3) & 63, rest = ii >> 9;
      int s = rest & 31, cb = rest >> 5;
      int k = s * 32 + ((l >> 4) << 3) + j, n = (cb << 4) + (l & 15);
      Waf[ii] = f2bf(Wout[k * 1536 + n]);
    } else {                                // WbT[v][k] = Wout[k][512+v]
      int ii = i - 1310720;
      int v = ii >> 10, k = ii & 1023;
      WbT[ii] = f2bf(Wout[k * 1536 + 512 + v]);
    }
  }
}

// ---------------------------------------------------------------------------
// Persistent recurrence kernel. 64 blocks x 256 threads.
// group g = blockIdx>>4 owns batch rows [16g,16g+16); member m = blockIdx&15
// owns output cols [32m, 32m+32). Waves K-split 4-ways, LDS reduce.
// ---------------------------------------------------------------------------
__device__ __forceinline__ void group_barrier(unsigned* __restrict__ cnt, int cidx) {
  __syncthreads();
  if (threadIdx.x == 0) {
    __threadfence();                     // release: make our slice stores visible
    atomicAdd(&cnt[cidx], 1u);
    int spins = 0;
    while (__hip_atomic_load(&cnt[cidx], __ATOMIC_RELAXED, __HIP_MEMORY_SCOPE_AGENT) < NG) {
      __builtin_amdgcn_s_sleep(2);
      if (++spins > (1 << 17)) { atomicMax(&cnt[cidx], (unsigned)NG); break; }
    }
    __threadfence();                     // acquire: invalidate before reading peers' data
  }
  __syncthreads();
}

__global__ __launch_bounds__(256, 1) void rnn_recur(
    const int* __restrict__ x, const float* __restrict__ emb,
    const float* __restrict__ b0, const float* __restrict__ b1,
    const float* __restrict__ bout,
    const short* __restrict__ W0f, const short* __restrict__ W1f,
    const short* __restrict__ Waf,
    short* __restrict__ cat, short* __restrict__ hbuf, unsigned* __restrict__ cnt) {
  const int tid = threadIdx.x;
  const int l = tid & 63, w = tid >> 6;
  const int g = blockIdx.x >> 4, m = blockIdx.x & 15;
  const int rowbase = g << 4, colbase = m << 5;
  __shared__ float red[2048];          // [wave][tile][row][col] = w*512 + tile*256 + r*16 + c

  // ---- load weight fragments into registers (held across the whole loop)
  short8 w0f[2][8], waf[2][8], w1f[2][4];
#pragma unroll
  for (int tile = 0; tile < 2; ++tile) {
    int cb = m * 2 + tile;
#pragma unroll
    for (int s = 0; s < 8; ++s)
      w0f[tile][s] = *(const short8*)&W0f[((cb * 32 + w * 8 + s) * 64 + l) * 8];
#pragma unroll
    for (int s = 0; s < 8; ++s)
      waf[tile][s] = *(const short8*)&Waf[((cb * 32 + w * 8 + s) * 64 + l) * 8];
#pragma unroll
    for (int s = 0; s < 4; ++s)
      w1f[tile][s] = *(const short8*)&W1f[((cb * 16 + w * 4 + s) * 64 + l) * 8];
  }

  const int rc = tid & 15, rr = tid >> 4;        // reduce-thread output coords
  const float bias0a = b0[colbase + rc],        bias0b = b0[colbase + 16 + rc];
  const float bias1a = b1[colbase + rc],        bias1b = b1[colbase + 16 + rc];
  const float biasOa = bout[colbase + rc],      biasOb = bout[colbase + 16 + rc];

  const int myrow = rowbase + (l & 15);
  const int kgrp = (l >> 4) * 8;

  for (int t = 0; t < T_; ++t) {
    // ================= phase 1: h0 = relu([e_t ; h] @ W0 + b0) =================
    {
      f32x4 acc0 = {0.f, 0.f, 0.f, 0.f}, acc1 = {0.f, 0.f, 0.f, 0.f};
      if (w < 2) {
        int idx = x[myrow * T_ + t];
        const float* erow = emb + (long)idx * STATE_ + w * 256 + kgrp;
#pragma unroll
        for (int s = 0; s < 8; ++s) {
          const float* p = erow + s * 32;
          short8 a;
#pragma unroll
          for (int j = 0; j < 8; ++j) a[j] = f2bf(p[j]);
          acc0 = MFMA16(a, w0f[0][s], acc0);
          acc1 = MFMA16(a, w0f[1][s], acc1);
        }
      } else {
        const short* hrow = hbuf + ((t & 1) << 15) + (myrow << 9) + (w - 2) * 256 + kgrp;
#pragma unroll
        for (int s = 0; s < 8; ++s) {
          short8 a = *(const short8*)(hrow + s * 32);
          acc0 = MFMA16(a, w0f[0][s], acc0);
          acc1 = MFMA16(a, w0f[1][s], acc1);
        }
      }
#pragma unroll
      for (int j = 0; j < 4; ++j) {
        red[w * 512 +       ((l >> 4) * 4 + j) * 16 + (l & 15)] = acc0[j];
        red[w * 512 + 256 + ((l >> 4) * 4 + j) * 16 + (l & 15)] = acc1[j];
      }
      __syncthreads();
      float v0 = red[rr * 16 + rc] + red[512 + rr * 16 + rc] + red[1024 + rr * 16 + rc] +
                 red[1536 + rr * 16 + rc] + bias0a;
      float v1 = red[256 + rr * 16 + rc] + red[768 + rr * 16 + rc] + red[1280 + rr * 16 + rc] +
                 red[1792 + rr * 16 + rc] + bias0b;
      v0 = fmaxf(v0, 0.f); v1 = fmaxf(v1, 0.f);
      int base = (t * B_ + rowbase + rr) * 1024 + colbase;
      cat[base + rc]      = f2bf(v0);
      cat[base + 16 + rc] = f2bf(v1);
    }
    group_barrier(cnt, (t * 3 + 0) * NGROUPS + g);

    // ================= phase 2: h1 = relu(h0 @ W1 + b1) =================
    {
      f32x4 acc0 = {0.f, 0.f, 0.f, 0.f}, acc1 = {0.f, 0.f, 0.f, 0.f};
      const short* crow = cat + (t * B_ + myrow) * 1024 + w * 128 + kgrp;
#pragma unroll
      for (int s = 0; s < 4; ++s) {
        short8 a = *(const short8*)(crow + s * 32);
        acc0 = MFMA16(a, w1f[0][s], acc0);
        acc1 = MFMA16(a, w1f[1][s], acc1);
      }
#pragma unroll
      for (int j = 0; j < 4; ++j) {
        red[w * 512 +       ((l >> 4) * 4 + j) * 16 + (l & 15)] = acc0[j];
        red[w * 512 + 256 + ((l >> 4) * 4 + j) * 16 + (l & 15)] = acc1[j];
      }
      __syncthreads();
      float v0 = red[rr * 16 + rc] + red[512 + rr * 16 + rc] + red[1024 + rr * 16 + rc] +
                 red[1536 + rr * 16 + rc] + bias1a;
      float v1 = red[256 + rr * 16 + rc] + red[768 + rr * 16 + rc] + red[1280 + rr * 16 + rc] +
                 red[1792 + rr * 16 + rc] + bias1b;
      v0 = fmaxf(v0, 0.f); v1 = fmaxf(v1, 0.f);
      int base = (t * B_ + rowbase + rr) * 1024 + 512 + colbase;
      cat[base + rc]      = f2bf(v0);
      cat[base + 16 + rc] = f2bf(v1);
    }
    if (t == T_ - 1) break;              // last h1 only feeds the logits GEMM (kernel boundary)
    group_barrier(cnt, (t * 3 + 1) * NGROUPS + g);

    // ================= phase 3: h_new = relu([h0,h1] @ Wout[:,:512] + bout[:512]) =================
    {
      f32x4 acc0 = {0.f, 0.f, 0.f, 0.f}, acc1 = {0.f, 0.f, 0.f, 0.f};
      const short* crow = cat + (t * B_ + myrow) * 1024 + w * 256 + kgrp;
#pragma unroll
      for (int s = 0; s < 8; ++s) {
        short8 a = *(const short8*)(crow + s * 32);
        acc0 = MFMA16(a, waf[0][s], acc0);
        acc1 = MFMA16(a, waf[1][s], acc1);
      }
#pragma unroll
      for (int j = 0; j < 4; ++j) {
        red[w * 512 +       ((l >> 4) * 4 + j) * 16 + (l & 15)] = acc0[j];
        red[w * 512 + 256 + ((l >> 4) * 4 + j) * 16 + (l & 15)] = acc1[j];
      }
      __syncthreads();
      float v0 = red[rr * 16 + rc] + red[512 + rr * 16 + rc] + red[1024 + rr * 16 + rc] +
                 red[1536 + rr * 16 + rc] + biasOa;
      float v1 = red[256 + rr * 16 + rc] + red[768 + rr * 16 + rc] + red[1280 + rr * 16 + rc] +
                 red[1792 + rr * 16 + rc] + biasOb;
      v0 = fmaxf(v0, 0.f); v1 = fmaxf(v1, 0.f);
      int base = (((t + 1) & 1) << 15) + (rowbase + rr) * 512 + colbase;
      hbuf[base + rc]      = f2bf(v0);
      hbuf[base + 16 + rc] = f2bf(v1);
    }
    group_barrier(cnt, (t * 3 + 2) * NGROUPS + g);
  }
}

// ---------------------------------------------------------------------------
// Logits GEMM: out[b][t][v] = cat[t*64+b][:] @ WbT[v][:] + bout[512+v]
// 128x128 tiles, 4 waves of 64x64 (4x4 16x16 frags), K-step 32, LDS staged.
// ---------------------------------------------------------------------------
__global__ __launch_bounds__(256) void logits_gemm(const short* __restrict__ cat,
                                                   const short* __restrict__ WbT,
                                                   const float* __restrict__ bout,
                                                   float* __restrict__ out) {
  const int mbase = (blockIdx.x >> 3) * 128;
  const int vbase = (blockIdx.x & 7) * 128;
  __shared__ short sA[128 * 32];
  __shared__ short sB[128 * 32];
  const int tid = threadIdx.x, l = tid & 63, w = tid >> 6;
  const int wm = w & 1, wn = w >> 1;

  f32x4 acc[4][4];
#pragma unroll
  for (int i = 0; i < 4; ++i)
#pragma unroll
    for (int j = 0; j < 4; ++j) acc[i][j] = (f32x4){0.f, 0.f, 0.f, 0.f};

  for (int kb = 0; kb < 1024; kb += 32) {
    __syncthreads();
#pragma unroll
    for (int it = 0; it < 2; ++it) {
      int c = tid + 256 * it;            // 0..511
      int ml = c >> 2, ks = c & 3;
      *(short8*)&sA[ml * 32 + ks * 8] = *(const short8*)&cat[(mbase + ml) * 1024 + kb + ks * 8];
      *(short8*)&sB[ml * 32 + ks * 8] = *(const short8*)&WbT[(vbase + ml) * 1024 + kb + ks * 8];
    }
    __syncthreads();
    short8 af[4], bf[4];
#pragma unroll
    for (int fr = 0; fr < 4; ++fr)
      af[fr] = *(const short8*)&sA[(wm * 64 + fr * 16 + (l & 15)) * 32 + (l >> 4) * 8];
#pragma unroll
    for (int fc = 0; fc < 4; ++fc)
      bf[fc] = *(const short8*)&sB[(wn * 64 + fc * 16 + (l & 15)) * 32 + (l >> 4) * 8];
#pragma unroll
    for (int fr = 0; fr < 4; ++fr)
#pragma unroll
      for (int fc = 0; fc < 4; ++fc) acc[fr][fc] = MFMA16(af[fr], bf[fc], acc[fr][fc]);
  }

  float bb[4];
#pragma unroll
  for (int fc = 0; fc < 4; ++fc) bb[fc] = bout[512 + vbase + wn * 64 + fc * 16 + (l & 15)];

#pragma unroll
  for (int fr = 0; fr < 4; ++fr) {
#pragma unroll
    for (int fc = 0; fc < 4; ++fc) {
      int v = vbase + wn * 64 + fc * 16 + (l & 15);
#pragma unroll
      for (int j = 0; j < 4; ++j) {
        int mm = mbase + wm * 64 + fr * 16 + (l >> 4) * 4 + j;
        int b = mm & 63, tt = mm >> 6;
        out[((long)(b * T_ + tt)) * 1024 + v] = acc[fr][fc][j] + bb[fc];
      }
    }
  }
}

extern "C" void kernel_launch(void* const* d_in, const int* in_sizes, int n_in,
                              void* d_out, int out_size, void* d_ws, size_t ws_size,
                              hipStream_t stream) {
  const int*   x    = (const int*)d_in[0];
  const float* emb  = (const float*)d_in[1];
  const float* W0   = (const float*)d_in[2];
  const float* b0   = (const float*)d_in[3];
  const float* W1   = (const float*)d_in[4];
  const float* b1   = (const float*)d_in[5];
  const float* Wout = (const float*)d_in[6];
  const float* bout = (const float*)d_in[7];
  float* out = (float*)d_out;

  char* ws = (char*)d_ws;
  unsigned* cnt = (unsigned*)(ws + CNT_OFF);
  short* hbuf = (short*)(ws + HBUF_OFF);
  short* cat  = (short*)(ws + CAT_OFF);
  short* W0f  = (short*)(ws + W0F_OFF);
  short* W1f  = (short*)(ws + W1F_OFF);
  short* Waf  = (short*)(ws + WAF_OFF);
  short* WbT  = (short*)(ws + WBT_OFF);

  // zero sync counters + h0 state (also provides h_init = 0)
  hipMemsetAsync(ws, 0, HBUF_OFF + 131072u, stream);
  pack_weights<<<1024, 256, 0, stream>>>(W0, W1, Wout, W0f, W1f, Waf, WbT);
  rnn_recur<<<64, 256, 0, stream>>>(x, emb, b0, b1, bout, W0f, W1f, Waf, cat, hbuf, cnt);
  logits_gemm<<<2048, 256, 0, stream>>>(cat, WbT, bout, out);
}

// Round 2
// 6368.052 us; speedup vs baseline: 1.4720x; 1.4720x over previous
//
#include <hip/hip_runtime.h>
#include <hip/hip_bf16.h>

typedef __attribute__((ext_vector_type(8))) short short8;
typedef __attribute__((ext_vector_type(4))) float f32x4;
typedef __attribute__((ext_vector_type(2))) unsigned long long u64x2;

#define MFMA16(a, b, c) __builtin_amdgcn_mfma_f32_16x16x32_bf16((a), (b), (c), 0, 0, 0)

// sizes
#define B_ 64
#define T_ 512
#define STATE_ 512
#define NG 16   // workgroups per row-group
#define NGROUPS 4

// ws layout (bytes)
#define CNT_OFF   0u          // flags: 4 groups * 16 members * 4B = 256 (64B line per group)
#define HBUF_OFF  24576u      // 2 * 64 * 512 * 2B = 131072
#define CAT_OFF   155648u     // 512*64*1024*2 = 67108864
#define W0F_OFF   67264512u   // 1048576
#define W1F_OFF   68313088u   // 524288
#define WAF_OFF   68837376u   // 1048576
#define WBT_OFF   69885952u   // 2097152
// end: 71983104

__device__ __forceinline__ short f2bf(float f) {
  unsigned u = __float_as_uint(f);
  unsigned r = (u + 0x7fffu + ((u >> 16) & 1u)) >> 16;
  return (short)r;
}

// agent-scope coherent 16B load (2 x b64 relaxed atomics, bypass stale L1/L2)
__device__ __forceinline__ short8 ld8(const short* p) {
  union { u64x2 q; short8 s; } u;
  u.q.x = __hip_atomic_load((const unsigned long long*)p, __ATOMIC_RELAXED, __HIP_MEMORY_SCOPE_AGENT);
  u.q.y = __hip_atomic_load(((const unsigned long long*)p) + 1, __ATOMIC_RELAXED, __HIP_MEMORY_SCOPE_AGENT);
  return u.s;
}

// agent-scope coherent store of 2 bf16 packed in a u32 (write-through to LLC)
__device__ __forceinline__ void st2(short* p, float v0, float v1) {
  unsigned pk = ((unsigned)(unsigned short)f2bf(v1) << 16) | (unsigned)(unsigned short)f2bf(v0);
  __hip_atomic_store((unsigned*)p, pk, __ATOMIC_RELAXED, __HIP_MEMORY_SCOPE_AGENT);
}

// ---------------------------------------------------------------------------
// Weight packing: fp32 -> bf16, MFMA B-fragment order for W0 / W1 / Wout[:, :512],
// plus transposed row-major copy of Wout[:, 512:] for the logits GEMM.
// Fragment blob layout for (K,N) matrix: idx = ((cb*(K/32) + s)*64 + l)*8 + j
//   holds W[s*32 + (l>>4)*8 + j][cb*16 + (l&15)]
// ---------------------------------------------------------------------------
__global__ void pack_weights(const float* __restrict__ W0, const float* __restrict__ W1,
                             const float* __restrict__ Wout,
                             short* __restrict__ W0f, short* __restrict__ W1f,
                             short* __restrict__ Waf, short* __restrict__ WbT) {
  const int total = 524288 + 262144 + 524288 + 1048576;
  for (int i = blockIdx.x * blockDim.x + threadIdx.x; i < total; i += gridDim.x * blockDim.x) {
    if (i < 524288) {                       // W0f: K=1024 (S=32), N=512
      int j = i & 7, l = (i >> 3) & 63, rest = i >> 9;
      int s = rest & 31, cb = rest >> 5;
      int k = s * 32 + ((l >> 4) << 3) + j, n = (cb << 4) + (l & 15);
      W0f[i] = f2bf(W0[k * 512 + n]);
    } else if (i < 786432) {                // W1f: K=512 (S=16), N=512
      int ii = i - 524288;
      int j = ii & 7, l = (ii >> 3) & 63, rest = ii >> 9;
      int s = rest & 15, cb = rest >> 4;
      int k = s * 32 + ((l >> 4) << 3) + j, n = (cb << 4) + (l & 15);
      W1f[ii] = f2bf(W1[k * 512 + n]);
    } else if (i < 1310720) {               // Waf: Wout[:, :512], K=1024 (S=32)
      int ii = i - 786432;
      int j = ii & 7, l = (ii >> 3) & 63, rest = ii >> 9;
      int s = rest & 31, cb = rest >> 5;
      int k = s * 32 + ((l >> 4) << 3) + j, n = (cb << 4) + (l & 15);
      Waf[ii] = f2bf(Wout[k * 1536 + n]);
    } else {                                // WbT[v][k] = Wout[k][512+v]
      int ii = i - 1310720;
      int v = ii >> 10, k = ii & 1023;
      WbT[ii] = f2bf(Wout[k * 1536 + 512 + v]);
    }
  }
}

// ---------------------------------------------------------------------------
// Flags-array barrier: member m sets flags[g*16+m] = tag (monotonic, release),
// threads 0..15 poll the 16 member flags (relaxed; control-dep orders the
// subsequent coherent data loads). No cache-wide fences -> weights stay cached.
// ---------------------------------------------------------------------------
__device__ __forceinline__ void group_barrier(unsigned* __restrict__ flags, int g, int m,
                                              unsigned tag) {
  __syncthreads();   // all waves' data stores drained (vmcnt(0) before s_barrier)
  const int tid = threadIdx.x;
  if (tid == 0)
    __hip_atomic_store(&flags[(g << 4) + m], tag, __ATOMIC_RELEASE, __HIP_MEMORY_SCOPE_AGENT);
  if (tid < NG) {
    int spins = 0;
    while (__hip_atomic_load(&flags[(g << 4) + tid], __ATOMIC_RELAXED,
                             __HIP_MEMORY_SCOPE_AGENT) < tag) {
      if (++spins > (1 << 16)) break;     // deadlock stopgap: degrade, don't hang
    }
  }
  __syncthreads();
}

// per-thread reduce over the 4 waves' partial tiles in LDS
__device__ __forceinline__ float rsum(const float* red, int rr, int col) {
  int o = ((col >> 4) << 8) + rr * 16 + (col & 15);
  return red[o] + red[o + 512] + red[o + 1024] + red[o + 1536];
}

// ---------------------------------------------------------------------------
// Persistent recurrence kernel. 64 blocks x 256 threads.
// group g = blockIdx>>4 owns batch rows [16g,16g+16); member m = blockIdx&15
// owns output cols [32m, 32m+32). Waves K-split 4-ways, LDS reduce.
// Wout[:, :512] is split: lo half (K = h0) folded into phase 2 (reuses the h0
// fragments already loaded for W1), hi half (K = h1) in phase 3.
// ---------------------------------------------------------------------------
__global__ __launch_bounds__(256, 1) void rnn_recur(
    const int* __restrict__ x, const float* __restrict__ emb,
    const float* __restrict__ b0, const float* __restrict__ b1,
    const float* __restrict__ bout,
    const short* __restrict__ W0f, const short* __restrict__ W1f,
    const short* __restrict__ Waf,
    short* __restrict__ cat, short* __restrict__ hbuf, unsigned* __restrict__ flags) {
  const int tid = threadIdx.x;
  const int l = tid & 63, w = tid >> 6;
  const int g = blockIdx.x >> 4, m = blockIdx.x & 15;
  const int rowbase = g << 4, colbase = m << 5;
  __shared__ float red[2048];          // [wave][tile][row][col] = w*512 + tile*256 + r*16 + c

  // ---- load weight fragments into registers (held across the whole loop)
  short8 w0f[2][8], waL[2][4], waH[2][4], w1f[2][4];
#pragma unroll
  for (int tile = 0; tile < 2; ++tile) {
    int cb = m * 2 + tile;
#pragma unroll
    for (int s = 0; s < 8; ++s)
      w0f[tile][s] = *(const short8*)&W0f[((cb * 32 + w * 8 + s) * 64 + l) * 8];
#pragma unroll
    for (int s = 0; s < 4; ++s) {
      waL[tile][s] = *(const short8*)&Waf[((cb * 32 + w * 4 + s) * 64 + l) * 8];
      waH[tile][s] = *(const short8*)&Waf[((cb * 32 + 16 + w * 4 + s) * 64 + l) * 8];
      w1f[tile][s] = *(const short8*)&W1f[((cb * 16 + w * 4 + s) * 64 + l) * 8];
    }
  }

  const int cp = tid & 15, rr2 = tid >> 4;       // reduce-thread output coords (2 cols each)
  const float b0a = b0[colbase + 2 * cp],   b0b = b0[colbase + 2 * cp + 1];
  const float b1a = b1[colbase + 2 * cp],   b1b = b1[colbase + 2 * cp + 1];
  const float bOa = bout[colbase + 2 * cp], bOb = bout[colbase + 2 * cp + 1];

  const int myrow = rowbase + (l & 15);
  const int kgrp = (l >> 4) * 8;

  for (int t = 0; t < T_; ++t) {
    // ================= phase 1: h0 = relu([e_t ; h] @ W0 + b0) =================
    {
      f32x4 acc0 = {0.f, 0.f, 0.f, 0.f}, acc1 = {0.f, 0.f, 0.f, 0.f};
      if (w < 2) {
        int idx = x[myrow * T_ + t];
        const float* erow = emb + (long)idx * STATE_ + w * 256 + kgrp;
#pragma unroll
        for (int s = 0; s < 8; ++s) {
          const float* p = erow + s * 32;
          short8 a;
#pragma unroll
          for (int j = 0; j < 8; ++j) a[j] = f2bf(p[j]);
          acc0 = MFMA16(a, w0f[0][s], acc0);
          acc1 = MFMA16(a, w0f[1][s], acc1);
        }
      } else {
        const short* hrow = hbuf + ((t & 1) << 15) + (myrow << 9) + (w - 2) * 256 + kgrp;
#pragma unroll
        for (int s = 0; s < 8; ++s) {
          short8 a = ld8(hrow + s * 32);
          acc0 = MFMA16(a, w0f[0][s], acc0);
          acc1 = MFMA16(a, w0f[1][s], acc1);
        }
      }
#pragma unroll
      for (int j = 0; j < 4; ++j) {
        red[w * 512 +       ((l >> 4) * 4 + j) * 16 + (l & 15)] = acc0[j];
        red[w * 512 + 256 + ((l >> 4) * 4 + j) * 16 + (l & 15)] = acc1[j];
      }
      __syncthreads();
      float v0 = fmaxf(rsum(red, rr2, 2 * cp) + b0a, 0.f);
      float v1 = fmaxf(rsum(red, rr2, 2 * cp + 1) + b0b, 0.f);
      st2(&cat[(t * B_ + rowbase + rr2) * 1024 + colbase + 2 * cp], v0, v1);
    }
    group_barrier(flags, g, m, (unsigned)(t * 3 + 1));

    // ====== phase 2: h1 = relu(h0 @ W1 + b1); partial = h0 @ Wout[:512, :512] ======
    f32x4 accP0 = {0.f, 0.f, 0.f, 0.f}, accP1 = {0.f, 0.f, 0.f, 0.f};
    {
      f32x4 acc0 = {0.f, 0.f, 0.f, 0.f}, acc1 = {0.f, 0.f, 0.f, 0.f};
      const short* crow = cat + (t * B_ + myrow) * 1024 + w * 128 + kgrp;
#pragma unroll
      for (int s = 0; s < 4; ++s) {
        short8 a = ld8(crow + s * 32);
        acc0 = MFMA16(a, w1f[0][s], acc0);
        acc1 = MFMA16(a, w1f[1][s], acc1);
        accP0 = MFMA16(a, waL[0][s], accP0);
        accP1 = MFMA16(a, waL[1][s], accP1);
      }
#pragma unroll
      for (int j = 0; j < 4; ++j) {
        red[w * 512 +       ((l >> 4) * 4 + j) * 16 + (l & 15)] = acc0[j];
        red[w * 512 + 256 + ((l >> 4) * 4 + j) * 16 + (l & 15)] = acc1[j];
      }
      __syncthreads();
      float v0 = fmaxf(rsum(red, rr2, 2 * cp) + b1a, 0.f);
      float v1 = fmaxf(rsum(red, rr2, 2 * cp + 1) + b1b, 0.f);
      st2(&cat[(t * B_ + rowbase + rr2) * 1024 + 512 + colbase + 2 * cp], v0, v1);
    }
    if (t == T_ - 1) break;              // last h1 only feeds the logits GEMM (kernel boundary)
    group_barrier(flags, g, m, (unsigned)(t * 3 + 2));

    // ========== phase 3: h_new = relu(partial + h1 @ Wout[512:, :512] + bout) ==========
    {
      const short* crow = cat + (t * B_ + myrow) * 1024 + 512 + w * 128 + kgrp;
#pragma unroll
      for (int s = 0; s < 4; ++s) {
        short8 a = ld8(crow + s * 32);
        accP0 = MFMA16(a, waH[0][s], accP0);
        accP1 = MFMA16(a, waH[1][s], accP1);
      }
#pragma unroll
      for (int j = 0; j < 4; ++j) {
        red[w * 512 +       ((l >> 4) * 4 + j) * 16 + (l & 15)] = accP0[j];
        red[w * 512 + 256 + ((l >> 4) * 4 + j) * 16 + (l & 15)] = accP1[j];
      }
      __syncthreads();
      float v0 = fmaxf(rsum(red, rr2, 2 * cp) + bOa, 0.f);
      float v1 = fmaxf(rsum(red, rr2, 2 * cp + 1) + bOb, 0.f);
      st2(&hbuf[(((t + 1) & 1) << 15) + (rowbase + rr2) * 512 + colbase + 2 * cp], v0, v1);
    }
    group_barrier(flags, g, m, (unsigned)(t * 3 + 3));
  }
}

// ---------------------------------------------------------------------------
// Logits GEMM: out[b][t][v] = cat[t*64+b][:] @ WbT[v][:] + bout[512+v]
// 128x128 tiles, 4 waves of 64x64 (4x4 16x16 frags), K-step 32, LDS staged.
// ---------------------------------------------------------------------------
__global__ __launch_bounds__(256) void logits_gemm(const short* __restrict__ cat,
                                                   const short* __restrict__ WbT,
                                                   const float* __restrict__ bout,
                                                   float* __restrict__ out) {
  const int mbase = (blockIdx.x >> 3) * 128;
  const int vbase = (blockIdx.x & 7) * 128;
  __shared__ short sA[128 * 32];
  __shared__ short sB[128 * 32];
  const int tid = threadIdx.x, l = tid & 63, w = tid >> 6;
  const int wm = w & 1, wn = w >> 1;

  f32x4 acc[4][4];
#pragma unroll
  for (int i = 0; i < 4; ++i)
#pragma unroll
    for (int j = 0; j < 4; ++j) acc[i][j] = (f32x4){0.f, 0.f, 0.f, 0.f};

  for (int kb = 0; kb < 1024; kb += 32) {
    __syncthreads();
#pragma unroll
    for (int it = 0; it < 2; ++it) {
      int c = tid + 256 * it;            // 0..511
      int ml = c >> 2, ks = c & 3;
      *(short8*)&sA[ml * 32 + ks * 8] = *(const short8*)&cat[(mbase + ml) * 1024 + kb + ks * 8];
      *(short8*)&sB[ml * 32 + ks * 8] = *(const short8*)&WbT[(vbase + ml) * 1024 + kb + ks * 8];
    }
    __syncthreads();
    short8 af[4], bf[4];
#pragma unroll
    for (int fr = 0; fr < 4; ++fr)
      af[fr] = *(const short8*)&sA[(wm * 64 + fr * 16 + (l & 15)) * 32 + (l >> 4) * 8];
#pragma unroll
    for (int fc = 0; fc < 4; ++fc)
      bf[fc] = *(const short8*)&sB[(wn * 64 + fc * 16 + (l & 15)) * 32 + (l >> 4) * 8];
#pragma unroll
    for (int fr = 0; fr < 4; ++fr)
#pragma unroll
      for (int fc = 0; fc < 4; ++fc) acc[fr][fc] = MFMA16(af[fr], bf[fc], acc[fr][fc]);
  }

  float bb[4];
#pragma unroll
  for (int fc = 0; fc < 4; ++fc) bb[fc] = bout[512 + vbase + wn * 64 + fc * 16 + (l & 15)];

#pragma unroll
  for (int fr = 0; fr < 4; ++fr) {
#pragma unroll
    for (int fc = 0; fc < 4; ++fc) {
      int v = vbase + wn * 64 + fc * 16 + (l & 15);
#pragma unroll
      for (int j = 0; j < 4; ++j) {
        int mm = mbase + wm * 64 + fr * 16 + (l >> 4) * 4 + j;
        int b = mm & 63, tt = mm >> 6;
        out[((long)(b * T_ + tt)) * 1024 + v] = acc[fr][fc][j] + bb[fc];
      }
    }
  }
}

extern "C" void kernel_launch(void* const* d_in, const int* in_sizes, int n_in,
                              void* d_out, int out_size, void* d_ws, size_t ws_size,
                              hipStream_t stream) {
  const int*   x    = (const int*)d_in[0];
  const float* emb  = (const float*)d_in[1];
  const float* W0   = (const float*)d_in[2];
  const float* b0   = (const float*)d_in[3];
  const float* W1   = (const float*)d_in[4];
  const float* b1   = (const float*)d_in[5];
  const float* Wout = (const float*)d_in[6];
  const float* bout = (const float*)d_in[7];
  float* out = (float*)d_out;

  char* ws = (char*)d_ws;
  unsigned* flags = (unsigned*)(ws + CNT_OFF);
  short* hbuf = (short*)(ws + HBUF_OFF);
  short* cat  = (short*)(ws + CAT_OFF);
  short* W0f  = (short*)(ws + W0F_OFF);
  short* W1f  = (short*)(ws + W1F_OFF);
  short* Waf  = (short*)(ws + WAF_OFF);
  short* WbT  = (short*)(ws + WBT_OFF);

  // zero sync flags + h0 state (also provides h_init = 0)
  hipMemsetAsync(ws, 0, HBUF_OFF + 131072u, stream);
  pack_weights<<<1024, 256, 0, stream>>>(W0, W1, Wout, W0f, W1f, Waf, WbT);
  rnn_recur<<<64, 256, 0, stream>>>(x, emb, b0, b1, bout, W0f, W1f, Waf, cat, hbuf, flags);
  logits_gemm<<<2048, 256, 0, stream>>>(cat, WbT, bout, out);
}